// Round 1
// baseline (23630.904 us; speedup 1.0000x reference)
//
#include <hip/hip_runtime.h>
#include <stdint.h>

#define HIST 1792
#define TGT 256
#define SEQ 2048
#define INPUT 352
#define EHID 250
#define HID 500

typedef _Float16 h2_t __attribute__((ext_vector_type(2)));

static __device__ __forceinline__ float fdot2(uint32_t a, uint32_t b, float c) {
  return __builtin_amdgcn_fdot2(__builtin_bit_cast(h2_t, a),
                                __builtin_bit_cast(h2_t, b), c, false);
}
static __device__ __forceinline__ uint32_t packh2(float lo, float hi) {
  h2_t h; h[0] = (_Float16)lo; h[1] = (_Float16)hi;
  return __builtin_bit_cast(uint32_t, h);
}
static __device__ __forceinline__ float sigf(float x) {
  x = fminf(fmaxf(x, -30.f), 30.f);
  return 1.f / (1.f + __expf(-x));
}
static __device__ __forceinline__ float tanh_f(float x) {
  x = fminf(fmaxf(x, -15.f), 15.f);
  float e = __expf(2.f * x);
  return (e - 1.f) / (e + 1.f);
}

// ---------------- embedding gather + target_emb ----------------
__global__ void k_embed(const int* __restrict__ loc, const int* __restrict__ tim,
                        const int* __restrict__ cid, const int* __restrict__ target,
                        const float* __restrict__ weight, const float* __restrict__ emb_tim_w,
                        const float* __restrict__ weight_cid,
                        float* __restrict__ x, float* __restrict__ te) {
  int t = blockIdx.x, tid = threadIdx.x;
  if (t < SEQ) {
    int l = loc[t], tm = tim[t], cd = cid[t];
    float* xr = x + (size_t)t * INPUT;
    for (int k = tid; k < 256; k += blockDim.x) xr[k] = weight[(size_t)l * 256 + k];
    for (int k = tid; k < 32; k += blockDim.x)  xr[256 + k] = emb_tim_w[tm * 32 + k];
    for (int k = tid; k < 64; k += blockDim.x)  xr[288 + k] = weight_cid[cd * 64 + k];
  } else {
    int i = t - SEQ;
    int tg = target[i];
    for (int k = tid; k < 256; k += blockDim.x) te[(size_t)i * 256 + k] = weight[(size_t)tg * 256 + k];
  }
}

// ---------------- C[M][N] = op(A)[M][K] @ W[N][K]^T + bias ----------------
__global__ void k_gemm_t(const float* __restrict__ A, int lda,
                         const float* __restrict__ W, const float* __restrict__ bias,
                         float* __restrict__ C, int ldc,
                         int M, int N, int K, int revA) {
  __shared__ float As[16][65];
  __shared__ float Ws[16][65];
  const int bn = blockIdx.x * 64, bm = blockIdx.y * 64;
  const int tid = threadIdx.x;
  const int tx = tid & 15, ty = tid >> 4;
  float acc[4][4] = {};
  for (int k0 = 0; k0 < K; k0 += 16) {
    for (int i = tid; i < 1024; i += 256) {
      int m = i >> 4, k = i & 15;
      int gm = bm + m, gk = k0 + k;
      float v = 0.f;
      if (gm < M && gk < K) { int am = revA ? (M - 1 - gm) : gm; v = A[(size_t)am * lda + gk]; }
      As[k][m] = v;
    }
    for (int i = tid; i < 1024; i += 256) {
      int n = i >> 4, k = i & 15;
      int gn = bn + n, gk = k0 + k;
      float v = 0.f;
      if (gn < N && gk < K) v = W[(size_t)gn * K + gk];
      Ws[k][n] = v;
    }
    __syncthreads();
#pragma unroll
    for (int k = 0; k < 16; k++) {
      float a0 = As[k][ty * 4 + 0], a1 = As[k][ty * 4 + 1], a2 = As[k][ty * 4 + 2], a3 = As[k][ty * 4 + 3];
      float b0 = Ws[k][tx * 4 + 0], b1 = Ws[k][tx * 4 + 1], b2 = Ws[k][tx * 4 + 2], b3 = Ws[k][tx * 4 + 3];
      acc[0][0] += a0 * b0; acc[0][1] += a0 * b1; acc[0][2] += a0 * b2; acc[0][3] += a0 * b3;
      acc[1][0] += a1 * b0; acc[1][1] += a1 * b1; acc[1][2] += a1 * b2; acc[1][3] += a1 * b3;
      acc[2][0] += a2 * b0; acc[2][1] += a2 * b1; acc[2][2] += a2 * b2; acc[2][3] += a2 * b3;
      acc[3][0] += a3 * b0; acc[3][1] += a3 * b1; acc[3][2] += a3 * b2; acc[3][3] += a3 * b3;
    }
    __syncthreads();
  }
  for (int i = 0; i < 4; i++) {
    int gm = bm + ty * 4 + i; if (gm >= M) continue;
    for (int j = 0; j < 4; j++) {
      int gn = bn + tx * 4 + j; if (gn >= N) continue;
      C[(size_t)gm * ldc + gn] = acc[i][j] + (bias ? bias[gn] : 0.f);
    }
  }
}

// ---------------- C[M][N] = A[M][K] @ B[K][N] + addvec[N] ----------------
__global__ void k_gemm_nn(const float* __restrict__ A, int lda,
                          const float* __restrict__ B, int ldb,
                          const float* __restrict__ addvec,
                          float* __restrict__ C, int ldc,
                          int M, int N, int K) {
  __shared__ float As[16][65];
  __shared__ float Bs[16][65];
  const int bn = blockIdx.x * 64, bm = blockIdx.y * 64;
  const int tid = threadIdx.x;
  const int tx = tid & 15, ty = tid >> 4;
  float acc[4][4] = {};
  for (int k0 = 0; k0 < K; k0 += 16) {
    for (int i = tid; i < 1024; i += 256) {
      int m = i >> 4, k = i & 15;
      int gm = bm + m, gk = k0 + k;
      float v = 0.f;
      if (gm < M && gk < K) v = A[(size_t)gm * lda + gk];
      As[k][m] = v;
    }
    for (int i = tid; i < 1024; i += 256) {
      int k = i >> 6, n = i & 63;
      int gk = k0 + k, gn = bn + n;
      float v = 0.f;
      if (gk < K && gn < N) v = B[(size_t)gk * ldb + gn];
      Bs[k][n] = v;
    }
    __syncthreads();
#pragma unroll
    for (int k = 0; k < 16; k++) {
      float a0 = As[k][ty * 4 + 0], a1 = As[k][ty * 4 + 1], a2 = As[k][ty * 4 + 2], a3 = As[k][ty * 4 + 3];
      float b0 = Bs[k][tx * 4 + 0], b1 = Bs[k][tx * 4 + 1], b2 = Bs[k][tx * 4 + 2], b3 = Bs[k][tx * 4 + 3];
      acc[0][0] += a0 * b0; acc[0][1] += a0 * b1; acc[0][2] += a0 * b2; acc[0][3] += a0 * b3;
      acc[1][0] += a1 * b0; acc[1][1] += a1 * b1; acc[1][2] += a1 * b2; acc[1][3] += a1 * b3;
      acc[2][0] += a2 * b0; acc[2][1] += a2 * b1; acc[2][2] += a2 * b2; acc[2][3] += a2 * b3;
      acc[3][0] += a3 * b0; acc[3][1] += a3 * b1; acc[3][2] += a3 * b2; acc[3][3] += a3 * b3;
    }
    __syncthreads();
  }
  for (int i = 0; i < 4; i++) {
    int gm = bm + ty * 4 + i; if (gm >= M) continue;
    for (int j = 0; j < 4; j++) {
      int gn = bn + tx * 4 + j; if (gn >= N) continue;
      C[(size_t)gm * ldc + gn] = acc[i][j] + (addvec ? addvec[gn] : 0.f);
    }
  }
}

// ---------------- LSTMs: b0=fwd enc, b1=bwd enc, b2+b3=decoder ----------------
__launch_bounds__(1024)
__global__ void k_lstm(const float* __restrict__ A_f, const float* __restrict__ A_b,
                       const float* __restrict__ A_d,
                       const float* __restrict__ Whh_f, const float* __restrict__ Whh_b,
                       const float* __restrict__ Whh_d,
                       float* __restrict__ hh, float* __restrict__ hdec,
                       float* ubuf, uint32_t* hbuf, int* flag_u, int* flag_h) {
  const int b = blockIdx.x;
  const int tid = threadIdx.x;
  if (b < 2) {
    // ---- encoder: 1000 rows, K=250. 500 threads x 2 rows, f16 weights in VGPRs.
    __shared__ uint4 h4[32];          // h packed f16: 250 halfs -> 128 dwords (padded 0)
    __shared__ float zbuf[1000];
    uint32_t* h2 = (uint32_t*)h4;
    const float* A = (b == 0) ? A_f : A_b;
    const float* Whh = (b == 0) ? Whh_f : Whh_b;
    uint32_t w0[128], w1[128];
    if (tid < 500) {
      const float* wr0 = Whh + (size_t)tid * EHID;
      const float* wr1 = Whh + (size_t)(tid + 500) * EHID;
#pragma unroll
      for (int m = 0; m < 125; m++) { w0[m] = packh2(wr0[2 * m], wr0[2 * m + 1]); w1[m] = packh2(wr1[2 * m], wr1[2 * m + 1]); }
#pragma unroll
      for (int m = 125; m < 128; m++) { w0[m] = 0; w1[m] = 0; }
    }
    if (tid < 32) h4[tid] = make_uint4(0, 0, 0, 0);
    float c = 0.f;
    __syncthreads();
    for (int t = 0; t < HIST; t++) {
      if (tid < 500) {
        float acc0 = A[t * 1000 + tid];
        float acc1 = A[t * 1000 + 500 + tid];
#pragma unroll
        for (int q = 0; q < 32; q++) {
          uint4 hq = h4[q];
          acc0 = fdot2(w0[4 * q + 0], hq.x, acc0);
          acc0 = fdot2(w0[4 * q + 1], hq.y, acc0);
          acc0 = fdot2(w0[4 * q + 2], hq.z, acc0);
          acc0 = fdot2(w0[4 * q + 3], hq.w, acc0);
          acc1 = fdot2(w1[4 * q + 0], hq.x, acc1);
          acc1 = fdot2(w1[4 * q + 1], hq.y, acc1);
          acc1 = fdot2(w1[4 * q + 2], hq.z, acc1);
          acc1 = fdot2(w1[4 * q + 3], hq.w, acc1);
        }
        zbuf[tid] = acc0;
        zbuf[500 + tid] = acc1;
      }
      __syncthreads();
      float hval = 0.f;
      if (tid < EHID) {
        float zi = zbuf[tid], zf = zbuf[250 + tid], zg = zbuf[500 + tid], zo = zbuf[750 + tid];
        c = sigf(zf) * c + sigf(zi) * tanh_f(zg);
        hval = sigf(zo) * tanh_f(c);
        if (b == 0) hh[(size_t)t * HID + tid] = hval;
        else        hh[(size_t)(HIST - 1 - t) * HID + EHID + tid] = hval;
      }
      float hother = __shfl_xor(hval, 1);
      if (tid < EHID && (tid & 1) == 0) h2[tid >> 1] = packh2(hval, hother);
      __syncthreads();
    }
  } else {
    // ---- decoder: 2000 rows, K=500, split over 2 blocks; per-step flag handshake.
    __shared__ uint4 h4[64];          // 500 halfs -> 256 dwords (padded 0)
    __shared__ float zb[1024];
    uint32_t* h2 = (uint32_t*)h4;
    const int half = tid >> 9;
    const int j = tid & 511;
    const bool act = (j < 500);
    int row;
    if (b == 2) row = half ? (1000 + j) : j;        // g : i
    else        row = half ? (1500 + j) : (500 + j); // o : f
    uint32_t w[256];
    if (act) {
      const float* wr = Whh_d + (size_t)row * HID;
#pragma unroll
      for (int m = 0; m < 250; m++) w[m] = packh2(wr[2 * m], wr[2 * m + 1]);
#pragma unroll
      for (int m = 250; m < 256; m++) w[m] = 0;
    }
    if (tid < 64) h4[tid] = make_uint4(0, 0, 0, 0);
    float c = 0.f;
    __syncthreads();
    for (int t = 0; t < TGT; t++) {
      float acc = 0.f;
      if (act) {
        acc = A_d[t * 2000 + row];
#pragma unroll
        for (int q = 0; q < 64; q++) {
          uint4 hq = h4[q];
          acc = fdot2(w[4 * q + 0], hq.x, acc);
          acc = fdot2(w[4 * q + 1], hq.y, acc);
          acc = fdot2(w[4 * q + 2], hq.z, acc);
          acc = fdot2(w[4 * q + 3], hq.w, acc);
        }
      }
      zb[tid] = acc;
      __syncthreads();
      if (b == 2) {
        if (half == 0 && act) {
          float zi = zb[tid], zg = zb[512 + tid];
          ubuf[j] = sigf(zi) * tanh_f(zg);
        }
        __threadfence();
        __syncthreads();
        if (tid == 0) {
          __hip_atomic_store(&flag_u[t], 1, __ATOMIC_RELEASE, __HIP_MEMORY_SCOPE_AGENT);
          while (__hip_atomic_load(&flag_h[t], __ATOMIC_ACQUIRE, __HIP_MEMORY_SCOPE_AGENT) == 0) {
            __builtin_amdgcn_s_sleep(2);
          }
        }
        __syncthreads();
        if (tid < 250) h2[tid] = __hip_atomic_load(&hbuf[tid], __ATOMIC_RELAXED, __HIP_MEMORY_SCOPE_AGENT);
        __syncthreads();
      } else {
        if (tid == 0) {
          while (__hip_atomic_load(&flag_u[t], __ATOMIC_ACQUIRE, __HIP_MEMORY_SCOPE_AGENT) == 0) {
            __builtin_amdgcn_s_sleep(2);
          }
        }
        __syncthreads();
        float hval = 0.f;
        if (half == 0 && act) {
          float zf = zb[tid], zo = zb[512 + tid];
          float u = __hip_atomic_load(&ubuf[j], __ATOMIC_RELAXED, __HIP_MEMORY_SCOPE_AGENT);
          c = sigf(zf) * c + u;
          hval = sigf(zo) * tanh_f(c);
          hdec[(size_t)t * HID + j] = hval;
        }
        float hother = __shfl_xor(hval, 1);
        if (half == 0 && act && (tid & 1) == 0) {
          uint32_t p = packh2(hval, hother);
          h2[tid >> 1] = p;
          hbuf[tid >> 1] = p;
        }
        __threadfence();
        __syncthreads();
        if (tid == 0) __hip_atomic_store(&flag_h[t], 1, __ATOMIC_RELEASE, __HIP_MEMORY_SCOPE_AGENT);
      }
    }
  }
}

// ---------------- attention tables: S1 (256x1792), S2 (256x256) ----------------
__global__ void k_attn(const int* __restrict__ loc, const int* __restrict__ tim,
                       const int* __restrict__ cid,
                       const float* __restrict__ ts, const float* __restrict__ pd,
                       const float* __restrict__ pct,
                       float* __restrict__ S1, float* __restrict__ S2) {
  const int i = blockIdx.x;
  const int tid = threadIdx.x; // 256
  __shared__ float e[HIST];
  __shared__ float red[256];
  const int loc_i = loc[HIST + i], tim_i = tim[HIST + i];
  // ---- history attentions (summed softmaxes) ----
  for (int tab = 0; tab < 3; tab++) {
    for (int jj = tid; jj < HIST; jj += 256) {
      float v;
      if (tab == 0)      v = 1.f / pd[(size_t)loc_i * 10000 + loc[jj]];
      else if (tab == 1) v = ts[tim_i * 48 + tim[jj]];
      else               v = pct[tim_i * 300 + cid[jj]];
      e[jj] = v;
    }
    __syncthreads();
    float mx = -1e30f;
    for (int jj = tid; jj < HIST; jj += 256) mx = fmaxf(mx, e[jj]);
    red[tid] = mx; __syncthreads();
    for (int s = 128; s > 0; s >>= 1) { if (tid < s) red[tid] = fmaxf(red[tid], red[tid + s]); __syncthreads(); }
    mx = red[0]; __syncthreads();
    float sm = 0.f;
    for (int jj = tid; jj < HIST; jj += 256) sm += __expf(e[jj] - mx);
    red[tid] = sm; __syncthreads();
    for (int s = 128; s > 0; s >>= 1) { if (tid < s) red[tid] += red[tid + s]; __syncthreads(); }
    float inv = 1.f / red[0]; __syncthreads();
    for (int jj = tid; jj < HIST; jj += 256) {
      float p = __expf(e[jj] - mx) * inv;
      if (tab == 0) S1[(size_t)i * HIST + jj] = p; else S1[(size_t)i * HIST + jj] += p;
    }
    __syncthreads();
  }
  // ---- self attentions (causal: upper triangle zeroed BEFORE softmax) ----
  const int lj = loc[HIST + tid], tj = tim[HIST + tid], cj = cid[HIST + tid];
  for (int tab = 0; tab < 3; tab++) {
    float v;
    if (tab == 0)      v = 1.f / pd[(size_t)loc_i * 10000 + lj];
    else if (tab == 1) v = ts[tim_i * 48 + tj];
    else               v = pct[tim_i * 300 + cj];
    if (tid > i) v = 0.f;
    red[tid] = v; __syncthreads();
    for (int s = 128; s > 0; s >>= 1) { if (tid < s) red[tid] = fmaxf(red[tid], red[tid + s]); __syncthreads(); }
    float mx = red[0]; __syncthreads();
    float ex = __expf(v - mx);
    red[tid] = ex; __syncthreads();
    for (int s = 128; s > 0; s >>= 1) { if (tid < s) red[tid] += red[tid + s]; __syncthreads(); }
    float p = ex / red[0]; __syncthreads();
    if (tab == 0) S2[(size_t)i * TGT + tid] = p; else S2[(size_t)i * TGT + tid] += p;
    __syncthreads();
  }
}

// ---------------- uid_emb = emb_uid_w[uid] @ fc_user_w^T + b ----------------
__global__ void k_uid(const int* __restrict__ uid, const float* __restrict__ emb_uid_w,
                      const float* __restrict__ fc_user_w, const float* __restrict__ fc_user_b,
                      float* __restrict__ uid_emb) {
  const int tid = threadIdx.x; // 512
  __shared__ float u[64];
  if (tid < 64) u[tid] = emb_uid_w[(size_t)uid[0] * 64 + tid];
  __syncthreads();
  if (tid < HID) {
    float a = fc_user_b[tid];
    for (int k = 0; k < 64; k++) a += u[k] * fc_user_w[tid * 64 + k];
    uid_emb[tid] = a;
  }
}

// ---------------- user attention + context_user -> out[:,1000:1500] ----------------
__global__ void k_user(const float* __restrict__ uid_emb, const float* __restrict__ hh,
                       float* __restrict__ out) {
  const int tid = threadIdx.x; // 1024
  __shared__ float s[HIST];
  __shared__ float red[1024];
  __shared__ float ue[HID];
  if (tid < HID) ue[tid] = uid_emb[tid];
  __syncthreads();
  for (int t = tid; t < HIST; t += 1024) {
    float a = 0.f;
    const float* hr = hh + (size_t)t * HID;
    for (int k = 0; k < HID; k++) a += ue[k] * hr[k];
    s[t] = a;
  }
  __syncthreads();
  float mx = -1e30f;
  for (int t = tid; t < HIST; t += 1024) mx = fmaxf(mx, s[t]);
  red[tid] = mx; __syncthreads();
  for (int st = 512; st > 0; st >>= 1) { if (tid < st) red[tid] = fmaxf(red[tid], red[tid + st]); __syncthreads(); }
  mx = red[0]; __syncthreads();
  float sm = 0.f;
  for (int t = tid; t < HIST; t += 1024) sm += __expf(s[t] - mx);
  red[tid] = sm; __syncthreads();
  for (int st = 512; st > 0; st >>= 1) { if (tid < st) red[tid] += red[tid + st]; __syncthreads(); }
  float inv = 1.f / red[0]; __syncthreads();
  for (int t = tid; t < HIST; t += 1024) s[t] = __expf(s[t] - mx) * inv;
  __syncthreads();
  if (tid < HID) {
    float a = 0.f;
    for (int t = 0; t < HIST; t++) a += s[t] * hh[(size_t)t * HID + tid];
    for (int i = 0; i < TGT; i++) out[(size_t)i * 1500 + 1000 + tid] = a;
  }
}

// ---------------- in-place log-softmax over rows of y[256][10000] ----------------
__global__ void k_logsoftmax(float* __restrict__ y) {
  const int i = blockIdx.x;
  const int tid = threadIdx.x; // 1024
  float* r = y + (size_t)i * 10000;
  __shared__ float red[1024];
  float mx = -1e30f;
  for (int j = tid; j < 10000; j += 1024) mx = fmaxf(mx, r[j]);
  red[tid] = mx; __syncthreads();
  for (int s = 512; s > 0; s >>= 1) { if (tid < s) red[tid] = fmaxf(red[tid], red[tid + s]); __syncthreads(); }
  mx = red[0]; __syncthreads();
  float sm = 0.f;
  for (int j = tid; j < 10000; j += 1024) sm += __expf(r[j] - mx);
  red[tid] = sm; __syncthreads();
  for (int s = 512; s > 0; s >>= 1) { if (tid < s) red[tid] += red[tid + s]; __syncthreads(); }
  float lse = mx + __logf(red[0]);
  __syncthreads();
  for (int j = tid; j < 10000; j += 1024) r[j] = r[j] - lse;
}

extern "C" void kernel_launch(void* const* d_in, const int* in_sizes, int n_in,
                              void* d_out, int out_size, void* d_ws, size_t ws_size,
                              hipStream_t stream) {
  (void)in_sizes; (void)n_in; (void)out_size; (void)ws_size;
  const int* loc = (const int*)d_in[0];
  const int* tim = (const int*)d_in[1];
  const int* cid = (const int*)d_in[2];
  const int* uid = (const int*)d_in[3];
  const int* target = (const int*)d_in[4];
  // d_in[5] = target_len (fixed 256)
  const float* ts = (const float*)d_in[6];
  const float* pd = (const float*)d_in[7];
  const float* pct = (const float*)d_in[8];
  const float* weight = (const float*)d_in[9];
  const float* weight_cid = (const float*)d_in[10];
  const float* emb_uid_w = (const float*)d_in[11];
  const float* emb_tim_w = (const float*)d_in[12];
  const float* enc_Wih_f = (const float*)d_in[13];
  const float* enc_Whh_f = (const float*)d_in[14];
  const float* enc_b_f = (const float*)d_in[15];
  const float* enc_Wih_b = (const float*)d_in[16];
  const float* enc_Whh_b = (const float*)d_in[17];
  const float* enc_b_b = (const float*)d_in[18];
  const float* dec_Wih = (const float*)d_in[19];
  const float* dec_Whh = (const float*)d_in[20];
  const float* dec_b = (const float*)d_in[21];
  const float* fc_user_w = (const float*)d_in[22];
  const float* fc_user_b = (const float*)d_in[23];
  const float* fc_final_w = (const float*)d_in[24];
  const float* fc_final_b = (const float*)d_in[25];
  const float* fc_final2_w = (const float*)d_in[26];
  const float* fc_final2_b = (const float*)d_in[27];

  float* score = (float*)d_out;                  // 256*10000
  float* y1 = score + (size_t)TGT * 10000;       // 256*500
  float* te = y1 + (size_t)TGT * HID;            // 256*256

  float* ws = (float*)d_ws;
  float* x = ws;                                  // SEQ*INPUT
  float* A_f = x + (size_t)SEQ * INPUT;           // HIST*1000
  float* A_b = A_f + (size_t)HIST * 1000;         // HIST*1000
  float* A_d = A_b + (size_t)HIST * 1000;         // TGT*2000
  float* hh = A_d + (size_t)TGT * 2000;           // HIST*500
  float* hdec = hh + (size_t)HIST * HID;          // TGT*500
  float* S1 = hdec + (size_t)TGT * HID;           // TGT*HIST
  float* S2 = S1 + (size_t)TGT * HIST;            // TGT*TGT
  float* outb = S2 + (size_t)TGT * TGT;           // TGT*1500
  float* uid_emb = outb + (size_t)TGT * 1500;     // 512
  float* ubuf = uid_emb + 512;                    // 512
  uint32_t* hbuf = (uint32_t*)(ubuf + 512);       // 256
  int* flag_u = (int*)(hbuf + 256);               // TGT
  int* flag_h = flag_u + TGT;                     // TGT

  k_embed<<<dim3(SEQ + TGT), dim3(128), 0, stream>>>(loc, tim, cid, target, weight, emb_tim_w, weight_cid, x, te);

  k_gemm_t<<<dim3(16, 28), dim3(256), 0, stream>>>(x, INPUT, enc_Wih_f, enc_b_f, A_f, 1000, HIST, 1000, INPUT, 0);
  k_gemm_t<<<dim3(16, 28), dim3(256), 0, stream>>>(x, INPUT, enc_Wih_b, enc_b_b, A_b, 1000, HIST, 1000, INPUT, 1);
  k_gemm_t<<<dim3(32, 4), dim3(256), 0, stream>>>(x + (size_t)HIST * INPUT, INPUT, dec_Wih, dec_b, A_d, 2000, TGT, 2000, INPUT, 0);

  hipMemsetAsync(flag_u, 0, 2 * TGT * sizeof(int), stream);

  k_attn<<<dim3(TGT), dim3(256), 0, stream>>>(loc, tim, cid, ts, pd, pct, S1, S2);
  k_uid<<<dim3(1), dim3(512), 0, stream>>>(uid, emb_uid_w, fc_user_w, fc_user_b, uid_emb);

  k_lstm<<<dim3(4), dim3(1024), 0, stream>>>(A_f, A_b, A_d, enc_Whh_f, enc_Whh_b, dec_Whh,
                                             hh, hdec, ubuf, hbuf, flag_u, flag_h);

  k_user<<<dim3(1), dim3(1024), 0, stream>>>(uid_emb, hh, outb);
  k_gemm_nn<<<dim3(8, 4), dim3(256), 0, stream>>>(S2, TGT, hdec, HID, uid_emb, outb, 1500, TGT, HID, TGT);
  k_gemm_nn<<<dim3(8, 4), dim3(256), 0, stream>>>(S1, HIST, hh, HID, nullptr, outb + 500, 1500, TGT, HID, HIST);

  k_gemm_t<<<dim3(157, 4), dim3(256), 0, stream>>>(outb, 1500, fc_final_w, fc_final_b, score, 10000, TGT, 10000, 1500, 0);
  k_gemm_t<<<dim3(8, 4), dim3(256), 0, stream>>>(outb, 1500, fc_final2_w, fc_final2_b, y1, 500, TGT, 500, 1500, 0);

  k_logsoftmax<<<dim3(TGT), dim3(1024), 0, stream>>>(score);
}

// Round 2
// 5403.259 us; speedup vs baseline: 4.3735x; 4.3735x over previous
//
#include <hip/hip_runtime.h>
#include <stdint.h>

#define HIST 1792
#define TGT 256
#define SEQ 2048
#define INPUT 352
#define EHID 250
#define HID 500

typedef _Float16 h2_t __attribute__((ext_vector_type(2)));

static __device__ __forceinline__ float fdot2(uint32_t a, uint32_t b, float c) {
  return __builtin_amdgcn_fdot2(__builtin_bit_cast(h2_t, a),
                                __builtin_bit_cast(h2_t, b), c, false);
}
static __device__ __forceinline__ uint32_t packh2(float lo, float hi) {
  h2_t h; h[0] = (_Float16)lo; h[1] = (_Float16)hi;
  return __builtin_bit_cast(uint32_t, h);
}
static __device__ __forceinline__ uint4 packq(const float* p) {
  uint4 r;
  r.x = packh2(p[0], p[1]); r.y = packh2(p[2], p[3]);
  r.z = packh2(p[4], p[5]); r.w = packh2(p[6], p[7]);
  return r;
}
static __device__ __forceinline__ float dotq(uint4 w, uint4 h, float acc) {
  acc = fdot2(w.x, h.x, acc); acc = fdot2(w.y, h.y, acc);
  acc = fdot2(w.z, h.z, acc); acc = fdot2(w.w, h.w, acc);
  return acc;
}
static __device__ __forceinline__ float sigf(float x) {
  x = fminf(fmaxf(x, -30.f), 30.f);
  return 1.f / (1.f + __expf(-x));
}
static __device__ __forceinline__ float tanh_f(float x) {
  x = fminf(fmaxf(x, -15.f), 15.f);
  float e = __expf(2.f * x);
  return (e - 1.f) / (e + 1.f);
}

// ---------------- embedding gather + target_emb ----------------
__global__ void k_embed(const int* __restrict__ loc, const int* __restrict__ tim,
                        const int* __restrict__ cid, const int* __restrict__ target,
                        const float* __restrict__ weight, const float* __restrict__ emb_tim_w,
                        const float* __restrict__ weight_cid,
                        float* __restrict__ x, float* __restrict__ te) {
  int t = blockIdx.x, tid = threadIdx.x;
  if (t < SEQ) {
    int l = loc[t], tm = tim[t], cd = cid[t];
    float* xr = x + (size_t)t * INPUT;
    for (int k = tid; k < 256; k += blockDim.x) xr[k] = weight[(size_t)l * 256 + k];
    for (int k = tid; k < 32; k += blockDim.x)  xr[256 + k] = emb_tim_w[tm * 32 + k];
    for (int k = tid; k < 64; k += blockDim.x)  xr[288 + k] = weight_cid[cd * 64 + k];
  } else {
    int i = t - SEQ;
    int tg = target[i];
    for (int k = tid; k < 256; k += blockDim.x) te[(size_t)i * 256 + k] = weight[(size_t)tg * 256 + k];
  }
}

// ---------------- C[M][N] = op(A)[M][K] @ W[N][K]^T + bias ----------------
__global__ void k_gemm_t(const float* __restrict__ A, int lda,
                         const float* __restrict__ W, const float* __restrict__ bias,
                         float* __restrict__ C, int ldc,
                         int M, int N, int K, int revA) {
  __shared__ float As[16][65];
  __shared__ float Ws[16][65];
  const int bn = blockIdx.x * 64, bm = blockIdx.y * 64;
  const int tid = threadIdx.x;
  const int tx = tid & 15, ty = tid >> 4;
  float acc[4][4] = {};
  for (int k0 = 0; k0 < K; k0 += 16) {
    for (int i = tid; i < 1024; i += 256) {
      int m = i >> 4, k = i & 15;
      int gm = bm + m, gk = k0 + k;
      float v = 0.f;
      if (gm < M && gk < K) { int am = revA ? (M - 1 - gm) : gm; v = A[(size_t)am * lda + gk]; }
      As[k][m] = v;
    }
    for (int i = tid; i < 1024; i += 256) {
      int n = i >> 4, k = i & 15;
      int gn = bn + n, gk = k0 + k;
      float v = 0.f;
      if (gn < N && gk < K) v = W[(size_t)gn * K + gk];
      Ws[k][n] = v;
    }
    __syncthreads();
#pragma unroll
    for (int k = 0; k < 16; k++) {
      float a0 = As[k][ty * 4 + 0], a1 = As[k][ty * 4 + 1], a2 = As[k][ty * 4 + 2], a3 = As[k][ty * 4 + 3];
      float b0 = Ws[k][tx * 4 + 0], b1 = Ws[k][tx * 4 + 1], b2 = Ws[k][tx * 4 + 2], b3 = Ws[k][tx * 4 + 3];
      acc[0][0] += a0 * b0; acc[0][1] += a0 * b1; acc[0][2] += a0 * b2; acc[0][3] += a0 * b3;
      acc[1][0] += a1 * b0; acc[1][1] += a1 * b1; acc[1][2] += a1 * b2; acc[1][3] += a1 * b3;
      acc[2][0] += a2 * b0; acc[2][1] += a2 * b1; acc[2][2] += a2 * b2; acc[2][3] += a2 * b3;
      acc[3][0] += a3 * b0; acc[3][1] += a3 * b1; acc[3][2] += a3 * b2; acc[3][3] += a3 * b3;
    }
    __syncthreads();
  }
  for (int i = 0; i < 4; i++) {
    int gm = bm + ty * 4 + i; if (gm >= M) continue;
    for (int j = 0; j < 4; j++) {
      int gn = bn + tx * 4 + j; if (gn >= N) continue;
      C[(size_t)gm * ldc + gn] = acc[i][j] + (bias ? bias[gn] : 0.f);
    }
  }
}

// ---------------- C[M][N] = A[M][K] @ B[K][N] + addvec[N] ----------------
__global__ void k_gemm_nn(const float* __restrict__ A, int lda,
                          const float* __restrict__ B, int ldb,
                          const float* __restrict__ addvec,
                          float* __restrict__ C, int ldc,
                          int M, int N, int K) {
  __shared__ float As[16][65];
  __shared__ float Bs[16][65];
  const int bn = blockIdx.x * 64, bm = blockIdx.y * 64;
  const int tid = threadIdx.x;
  const int tx = tid & 15, ty = tid >> 4;
  float acc[4][4] = {};
  for (int k0 = 0; k0 < K; k0 += 16) {
    for (int i = tid; i < 1024; i += 256) {
      int m = i >> 4, k = i & 15;
      int gm = bm + m, gk = k0 + k;
      float v = 0.f;
      if (gm < M && gk < K) v = A[(size_t)gm * lda + gk];
      As[k][m] = v;
    }
    for (int i = tid; i < 1024; i += 256) {
      int k = i >> 6, n = i & 63;
      int gk = k0 + k, gn = bn + n;
      float v = 0.f;
      if (gk < K && gn < N) v = B[(size_t)gk * ldb + gn];
      Bs[k][n] = v;
    }
    __syncthreads();
#pragma unroll
    for (int k = 0; k < 16; k++) {
      float a0 = As[k][ty * 4 + 0], a1 = As[k][ty * 4 + 1], a2 = As[k][ty * 4 + 2], a3 = As[k][ty * 4 + 3];
      float b0 = Bs[k][tx * 4 + 0], b1 = Bs[k][tx * 4 + 1], b2 = Bs[k][tx * 4 + 2], b3 = Bs[k][tx * 4 + 3];
      acc[0][0] += a0 * b0; acc[0][1] += a0 * b1; acc[0][2] += a0 * b2; acc[0][3] += a0 * b3;
      acc[1][0] += a1 * b0; acc[1][1] += a1 * b1; acc[1][2] += a1 * b2; acc[1][3] += a1 * b3;
      acc[2][0] += a2 * b0; acc[2][1] += a2 * b1; acc[2][2] += a2 * b2; acc[2][3] += a2 * b3;
      acc[3][0] += a3 * b0; acc[3][1] += a3 * b1; acc[3][2] += a3 * b2; acc[3][3] += a3 * b3;
    }
    __syncthreads();
  }
  for (int i = 0; i < 4; i++) {
    int gm = bm + ty * 4 + i; if (gm >= M) continue;
    for (int j = 0; j < 4; j++) {
      int gn = bn + tx * 4 + j; if (gn >= N) continue;
      C[(size_t)gm * ldc + gn] = acc[i][j] + (addvec ? addvec[gn] : 0.f);
    }
  }
}

// ---------------- LSTMs ----------------
// grid = 6 blocks x 512 threads:
//   b0 = fwd encoder, b1 = bwd encoder (1000x250 each, 2 rows/thread)
//   b2..b5 = decoder gates i,f,g,o (500 rows each, 1 row/thread, K=500)
// Weights f16-packed: 224 dwords in VGPR + 32 dwords in LDS per thread.
// __launch_bounds__(512,2): 8 waves/block, 2/SIMD -> 256 VGPR cap (no spill at ~250).
__launch_bounds__(512, 2)
__global__ void k_lstm(const float* __restrict__ A_f, const float* __restrict__ A_b,
                       const float* __restrict__ A_d,
                       const float* __restrict__ Whh_f, const float* __restrict__ Whh_b,
                       const float* __restrict__ Whh_d,
                       float* __restrict__ hh, float* __restrict__ hdec,
                       float* zpub, uint32_t* hpub, int* flag_z, int* flag_h) {
  const int b = blockIdx.x;
  const int tid = threadIdx.x;
  __shared__ uint4 h4e[32];        // encoder h: 256 halfs (250 + pad)
  __shared__ uint4 w4e[8][512];    // encoder LDS weight tail: 2 rows x 4 quads
  __shared__ float zbuf[1000];
  __shared__ uint4 h4d[64];        // decoder h: 512 halfs (500 + pad)
  __shared__ uint4 w4d[8][512];    // decoder LDS weight tail: 8 quads

  if (b < 2) {
    // ================= encoder =================
    const float* A = (b == 0) ? A_f : A_b;
    const float* Whh = (b == 0) ? Whh_f : Whh_b;
    uint4 w0[28], w1[28];
    if (tid < 500) {
      const float* wr0 = Whh + (size_t)tid * EHID;
      const float* wr1 = Whh + (size_t)(tid + 500) * EHID;
      // LDS tail first (keeps temp pressure away from the big VGPR arrays)
      float tmp[32];
#pragma unroll
      for (int cc = 0; cc < 32; cc++) { int col = 224 + cc; tmp[cc] = (col < EHID) ? wr0[col] : 0.f; }
#pragma unroll
      for (int k = 0; k < 4; k++) w4e[k][tid] = packq(tmp + 8 * k);
#pragma unroll
      for (int cc = 0; cc < 32; cc++) { int col = 224 + cc; tmp[cc] = (col < EHID) ? wr1[col] : 0.f; }
#pragma unroll
      for (int k = 0; k < 4; k++) w4e[4 + k][tid] = packq(tmp + 8 * k);
#pragma unroll
      for (int q = 0; q < 28; q++) { w0[q] = packq(wr0 + 8 * q); w1[q] = packq(wr1 + 8 * q); }
    }
    if (tid < 32) h4e[tid] = make_uint4(0, 0, 0, 0);
    uint32_t* hde = (uint32_t*)h4e;
    float c = 0.f;
    __syncthreads();
    for (int t = 0; t < HIST; t++) {
      if (tid < 500) {
        float a0 = A[t * 1000 + tid];
        float a1 = A[t * 1000 + 500 + tid];
        float b0 = 0.f, b1 = 0.f;
#pragma unroll
        for (int q = 0; q < 28; q += 2) {
          uint4 h0 = h4e[q], h1 = h4e[q + 1];
          a0 = dotq(w0[q], h0, a0);
          a1 = dotq(w1[q], h0, a1);
          b0 = dotq(w0[q + 1], h1, b0);
          b1 = dotq(w1[q + 1], h1, b1);
        }
#pragma unroll
        for (int k = 0; k < 4; k += 2) {
          uint4 h0 = h4e[28 + k], h1 = h4e[29 + k];
          a0 = dotq(w4e[k][tid], h0, a0);
          a1 = dotq(w4e[4 + k][tid], h0, a1);
          b0 = dotq(w4e[k + 1][tid], h1, b0);
          b1 = dotq(w4e[5 + k][tid], h1, b1);
        }
        zbuf[tid] = a0 + b0;
        zbuf[500 + tid] = a1 + b1;
      }
      __syncthreads();
      float hval = 0.f;
      if (tid < EHID) {
        float zi = zbuf[tid], zf = zbuf[250 + tid], zg = zbuf[500 + tid], zo = zbuf[750 + tid];
        c = sigf(zf) * c + sigf(zi) * tanh_f(zg);
        hval = sigf(zo) * tanh_f(c);
        if (b == 0) hh[(size_t)t * HID + tid] = hval;
        else        hh[(size_t)(HIST - 1 - t) * HID + EHID + tid] = hval;
      }
      float hother = __shfl_xor(hval, 1);
      if (tid < EHID && !(tid & 1)) hde[tid >> 1] = packh2(hval, hother);
      __syncthreads();
    }
  } else {
    // ================= decoder =================
    const int gi = b - 2;            // 0=i, 1=f, 2=g, 3=o
    const int j = tid;
    const bool act = (j < 500);
    uint4 w[56];
    if (act) {
      const float* wr = Whh_d + (size_t)(gi * 500 + j) * HID;
      float tmp[64];
#pragma unroll
      for (int cc = 0; cc < 64; cc++) { int col = 448 + cc; tmp[cc] = (col < HID) ? wr[col] : 0.f; }
#pragma unroll
      for (int k = 0; k < 8; k++) w4d[k][tid] = packq(tmp + 8 * k);
#pragma unroll
      for (int q = 0; q < 56; q++) w[q] = packq(wr + 8 * q);
    }
    if (tid < 64) h4d[tid] = make_uint4(0, 0, 0, 0);
    uint32_t* hdd = (uint32_t*)h4d;
    float c = 0.f;
    __syncthreads();
    for (int t = 0; t < TGT; t++) {
      float z = 0.f;
      if (act) {
        float a0 = A_d[t * 2000 + gi * 500 + j];
        float a1 = 0.f, a2 = 0.f, a3 = 0.f;
#pragma unroll
        for (int q = 0; q < 56; q += 4) {
          uint4 h0 = h4d[q], h1 = h4d[q + 1], h2 = h4d[q + 2], h3 = h4d[q + 3];
          a0 = dotq(w[q], h0, a0);
          a1 = dotq(w[q + 1], h1, a1);
          a2 = dotq(w[q + 2], h2, a2);
          a3 = dotq(w[q + 3], h3, a3);
        }
#pragma unroll
        for (int k = 0; k < 8; k += 4) {
          uint4 h0 = h4d[56 + k], h1 = h4d[57 + k], h2 = h4d[58 + k], h3 = h4d[59 + k];
          a0 = dotq(w4d[k][tid], h0, a0);
          a1 = dotq(w4d[k + 1][tid], h1, a1);
          a2 = dotq(w4d[k + 2][tid], h2, a2);
          a3 = dotq(w4d[k + 3][tid], h3, a3);
        }
        z = (a0 + a1) + (a2 + a3);
      }
      if (gi < 3) {
        // publish z, then wait for h
        if (act) zpub[gi * 512 + j] = z;
        __threadfence();
        __syncthreads();
        if (tid == 0)
          __hip_atomic_store(&flag_z[t * 3 + gi], 1, __ATOMIC_RELEASE, __HIP_MEMORY_SCOPE_AGENT);
        if (tid == 0) {
          while (__hip_atomic_load(&flag_h[t], __ATOMIC_ACQUIRE, __HIP_MEMORY_SCOPE_AGENT) == 0)
            __builtin_amdgcn_s_sleep(2);
        }
        __syncthreads();
        if (tid < 250)
          hdd[tid] = __hip_atomic_load(&hpub[tid], __ATOMIC_RELAXED, __HIP_MEMORY_SCOPE_AGENT);
        __syncthreads();
      } else {
        // o-gate block: gather z_i, z_f, z_g; own z_o; update c, h; publish h
        if (tid == 0) {
          while (__hip_atomic_load(&flag_z[t * 3 + 0], __ATOMIC_ACQUIRE, __HIP_MEMORY_SCOPE_AGENT) == 0)
            __builtin_amdgcn_s_sleep(2);
          while (__hip_atomic_load(&flag_z[t * 3 + 1], __ATOMIC_ACQUIRE, __HIP_MEMORY_SCOPE_AGENT) == 0)
            __builtin_amdgcn_s_sleep(2);
          while (__hip_atomic_load(&flag_z[t * 3 + 2], __ATOMIC_ACQUIRE, __HIP_MEMORY_SCOPE_AGENT) == 0)
            __builtin_amdgcn_s_sleep(2);
        }
        __syncthreads();
        float hval = 0.f;
        if (act) {
          float zi = __hip_atomic_load(&zpub[0 * 512 + j], __ATOMIC_RELAXED, __HIP_MEMORY_SCOPE_AGENT);
          float zf = __hip_atomic_load(&zpub[1 * 512 + j], __ATOMIC_RELAXED, __HIP_MEMORY_SCOPE_AGENT);
          float zg = __hip_atomic_load(&zpub[2 * 512 + j], __ATOMIC_RELAXED, __HIP_MEMORY_SCOPE_AGENT);
          c = sigf(zf) * c + sigf(zi) * tanh_f(zg);
          hval = sigf(z) * tanh_f(c);
          hdec[(size_t)t * HID + j] = hval;
        }
        float hother = __shfl_xor(hval, 1);
        if (act && !(j & 1)) {
          uint32_t p = packh2(hval, hother);
          hdd[j >> 1] = p;
          hpub[j >> 1] = p;
        }
        __threadfence();
        __syncthreads();
        if (tid == 0)
          __hip_atomic_store(&flag_h[t], 1, __ATOMIC_RELEASE, __HIP_MEMORY_SCOPE_AGENT);
      }
    }
  }
}

// ---------------- attention tables: S1 (256x1792), S2 (256x256) ----------------
__global__ void k_attn(const int* __restrict__ loc, const int* __restrict__ tim,
                       const int* __restrict__ cid,
                       const float* __restrict__ ts, const float* __restrict__ pd,
                       const float* __restrict__ pct,
                       float* __restrict__ S1, float* __restrict__ S2) {
  const int i = blockIdx.x;
  const int tid = threadIdx.x; // 256
  __shared__ float e[HIST];
  __shared__ float red[256];
  const int loc_i = loc[HIST + i], tim_i = tim[HIST + i];
  for (int tab = 0; tab < 3; tab++) {
    for (int jj = tid; jj < HIST; jj += 256) {
      float v;
      if (tab == 0)      v = 1.f / pd[(size_t)loc_i * 10000 + loc[jj]];
      else if (tab == 1) v = ts[tim_i * 48 + tim[jj]];
      else               v = pct[tim_i * 300 + cid[jj]];
      e[jj] = v;
    }
    __syncthreads();
    float mx = -1e30f;
    for (int jj = tid; jj < HIST; jj += 256) mx = fmaxf(mx, e[jj]);
    red[tid] = mx; __syncthreads();
    for (int s = 128; s > 0; s >>= 1) { if (tid < s) red[tid] = fmaxf(red[tid], red[tid + s]); __syncthreads(); }
    mx = red[0]; __syncthreads();
    float sm = 0.f;
    for (int jj = tid; jj < HIST; jj += 256) sm += __expf(e[jj] - mx);
    red[tid] = sm; __syncthreads();
    for (int s = 128; s > 0; s >>= 1) { if (tid < s) red[tid] += red[tid + s]; __syncthreads(); }
    float inv = 1.f / red[0]; __syncthreads();
    for (int jj = tid; jj < HIST; jj += 256) {
      float p = __expf(e[jj] - mx) * inv;
      if (tab == 0) S1[(size_t)i * HIST + jj] = p; else S1[(size_t)i * HIST + jj] += p;
    }
    __syncthreads();
  }
  const int lj = loc[HIST + tid], tj = tim[HIST + tid], cj = cid[HIST + tid];
  for (int tab = 0; tab < 3; tab++) {
    float v;
    if (tab == 0)      v = 1.f / pd[(size_t)loc_i * 10000 + lj];
    else if (tab == 1) v = ts[tim_i * 48 + tj];
    else               v = pct[tim_i * 300 + cj];
    if (tid > i) v = 0.f;
    red[tid] = v; __syncthreads();
    for (int s = 128; s > 0; s >>= 1) { if (tid < s) red[tid] = fmaxf(red[tid], red[tid + s]); __syncthreads(); }
    float mx = red[0]; __syncthreads();
    float ex = __expf(v - mx);
    red[tid] = ex; __syncthreads();
    for (int s = 128; s > 0; s >>= 1) { if (tid < s) red[tid] += red[tid + s]; __syncthreads(); }
    float p = ex / red[0]; __syncthreads();
    if (tab == 0) S2[(size_t)i * TGT + tid] = p; else S2[(size_t)i * TGT + tid] += p;
    __syncthreads();
  }
}

// ---------------- uid_emb ----------------
__global__ void k_uid(const int* __restrict__ uid, const float* __restrict__ emb_uid_w,
                      const float* __restrict__ fc_user_w, const float* __restrict__ fc_user_b,
                      float* __restrict__ uid_emb) {
  const int tid = threadIdx.x; // 512
  __shared__ float u[64];
  if (tid < 64) u[tid] = emb_uid_w[(size_t)uid[0] * 64 + tid];
  __syncthreads();
  if (tid < HID) {
    float a = fc_user_b[tid];
    for (int k = 0; k < 64; k++) a += u[k] * fc_user_w[tid * 64 + k];
    uid_emb[tid] = a;
  }
}

// ---------------- user attention + context_user ----------------
__global__ void k_user(const float* __restrict__ uid_emb, const float* __restrict__ hh,
                       float* __restrict__ out) {
  const int tid = threadIdx.x; // 1024
  __shared__ float s[HIST];
  __shared__ float red[1024];
  __shared__ float ue[HID];
  if (tid < HID) ue[tid] = uid_emb[tid];
  __syncthreads();
  for (int t = tid; t < HIST; t += 1024) {
    float a = 0.f;
    const float* hr = hh + (size_t)t * HID;
    for (int k = 0; k < HID; k++) a += ue[k] * hr[k];
    s[t] = a;
  }
  __syncthreads();
  float mx = -1e30f;
  for (int t = tid; t < HIST; t += 1024) mx = fmaxf(mx, s[t]);
  red[tid] = mx; __syncthreads();
  for (int st = 512; st > 0; st >>= 1) { if (tid < st) red[tid] = fmaxf(red[tid], red[tid + st]); __syncthreads(); }
  mx = red[0]; __syncthreads();
  float sm = 0.f;
  for (int t = tid; t < HIST; t += 1024) sm += __expf(s[t] - mx);
  red[tid] = sm; __syncthreads();
  for (int st = 512; st > 0; st >>= 1) { if (tid < st) red[tid] += red[tid + st]; __syncthreads(); }
  float inv = 1.f / red[0]; __syncthreads();
  for (int t = tid; t < HIST; t += 1024) s[t] = __expf(s[t] - mx) * inv;
  __syncthreads();
  if (tid < HID) {
    float a = 0.f;
    for (int t = 0; t < HIST; t++) a += s[t] * hh[(size_t)t * HID + tid];
    for (int i = 0; i < TGT; i++) out[(size_t)i * 1500 + 1000 + tid] = a;
  }
}

// ---------------- in-place log-softmax ----------------
__global__ void k_logsoftmax(float* __restrict__ y) {
  const int i = blockIdx.x;
  const int tid = threadIdx.x; // 1024
  float* r = y + (size_t)i * 10000;
  __shared__ float red[1024];
  float mx = -1e30f;
  for (int j = tid; j < 10000; j += 1024) mx = fmaxf(mx, r[j]);
  red[tid] = mx; __syncthreads();
  for (int s = 512; s > 0; s >>= 1) { if (tid < s) red[tid] = fmaxf(red[tid], red[tid + s]); __syncthreads(); }
  mx = red[0]; __syncthreads();
  float sm = 0.f;
  for (int j = tid; j < 10000; j += 1024) sm += __expf(r[j] - mx);
  red[tid] = sm; __syncthreads();
  for (int s = 512; s > 0; s >>= 1) { if (tid < s) red[tid] += red[tid + s]; __syncthreads(); }
  float lse = mx + __logf(red[0]);
  __syncthreads();
  for (int j = tid; j < 10000; j += 1024) r[j] = r[j] - lse;
}

extern "C" void kernel_launch(void* const* d_in, const int* in_sizes, int n_in,
                              void* d_out, int out_size, void* d_ws, size_t ws_size,
                              hipStream_t stream) {
  (void)in_sizes; (void)n_in; (void)out_size; (void)ws_size;
  const int* loc = (const int*)d_in[0];
  const int* tim = (const int*)d_in[1];
  const int* cid = (const int*)d_in[2];
  const int* uid = (const int*)d_in[3];
  const int* target = (const int*)d_in[4];
  const float* ts = (const float*)d_in[6];
  const float* pd = (const float*)d_in[7];
  const float* pct = (const float*)d_in[8];
  const float* weight = (const float*)d_in[9];
  const float* weight_cid = (const float*)d_in[10];
  const float* emb_uid_w = (const float*)d_in[11];
  const float* emb_tim_w = (const float*)d_in[12];
  const float* enc_Wih_f = (const float*)d_in[13];
  const float* enc_Whh_f = (const float*)d_in[14];
  const float* enc_b_f = (const float*)d_in[15];
  const float* enc_Wih_b = (const float*)d_in[16];
  const float* enc_Whh_b = (const float*)d_in[17];
  const float* enc_b_b = (const float*)d_in[18];
  const float* dec_Wih = (const float*)d_in[19];
  const float* dec_Whh = (const float*)d_in[20];
  const float* dec_b = (const float*)d_in[21];
  const float* fc_user_w = (const float*)d_in[22];
  const float* fc_user_b = (const float*)d_in[23];
  const float* fc_final_w = (const float*)d_in[24];
  const float* fc_final_b = (const float*)d_in[25];
  const float* fc_final2_w = (const float*)d_in[26];
  const float* fc_final2_b = (const float*)d_in[27];

  float* score = (float*)d_out;                  // 256*10000
  float* y1 = score + (size_t)TGT * 10000;       // 256*500
  float* te = y1 + (size_t)TGT * HID;            // 256*256

  float* ws = (float*)d_ws;
  float* x = ws;                                  // SEQ*INPUT
  float* A_f = x + (size_t)SEQ * INPUT;           // HIST*1000
  float* A_b = A_f + (size_t)HIST * 1000;         // HIST*1000
  float* A_d = A_b + (size_t)HIST * 1000;         // TGT*2000
  float* hh = A_d + (size_t)TGT * 2000;           // HIST*500
  float* hdec = hh + (size_t)HIST * HID;          // TGT*500
  float* S1 = hdec + (size_t)TGT * HID;           // TGT*HIST
  float* S2 = S1 + (size_t)TGT * HIST;            // TGT*TGT
  float* outb = S2 + (size_t)TGT * TGT;           // TGT*1500
  float* uid_emb = outb + (size_t)TGT * 1500;     // 512
  float* zpub = uid_emb + 512;                    // 3*512
  uint32_t* hpub = (uint32_t*)(zpub + 3 * 512);   // 256
  int* flag_z = (int*)(hpub + 256);               // 3*256
  int* flag_h = flag_z + 3 * TGT;                 // 256

  k_embed<<<dim3(SEQ + TGT), dim3(128), 0, stream>>>(loc, tim, cid, target, weight, emb_tim_w, weight_cid, x, te);

  k_gemm_t<<<dim3(16, 28), dim3(256), 0, stream>>>(x, INPUT, enc_Wih_f, enc_b_f, A_f, 1000, HIST, 1000, INPUT, 0);
  k_gemm_t<<<dim3(16, 28), dim3(256), 0, stream>>>(x, INPUT, enc_Wih_b, enc_b_b, A_b, 1000, HIST, 1000, INPUT, 1);
  k_gemm_t<<<dim3(32, 4), dim3(256), 0, stream>>>(x + (size_t)HIST * INPUT, INPUT, dec_Wih, dec_b, A_d, 2000, TGT, 2000, INPUT, 0);

  hipMemsetAsync(flag_z, 0, 4 * TGT * sizeof(int), stream);

  k_attn<<<dim3(TGT), dim3(256), 0, stream>>>(loc, tim, cid, ts, pd, pct, S1, S2);
  k_uid<<<dim3(1), dim3(512), 0, stream>>>(uid, emb_uid_w, fc_user_w, fc_user_b, uid_emb);

  k_lstm<<<dim3(6), dim3(512), 0, stream>>>(A_f, A_b, A_d, enc_Whh_f, enc_Whh_b, dec_Whh,
                                            hh, hdec, zpub, hpub, flag_z, flag_h);

  k_user<<<dim3(1), dim3(1024), 0, stream>>>(uid_emb, hh, outb);
  k_gemm_nn<<<dim3(8, 4), dim3(256), 0, stream>>>(S2, TGT, hdec, HID, uid_emb, outb, 1500, TGT, HID, TGT);
  k_gemm_nn<<<dim3(8, 4), dim3(256), 0, stream>>>(S1, HIST, hh, HID, nullptr, outb + 500, 1500, TGT, HID, HIST);

  k_gemm_t<<<dim3(157, 4), dim3(256), 0, stream>>>(outb, 1500, fc_final_w, fc_final_b, score, 10000, TGT, 10000, 1500, 0);
  k_gemm_t<<<dim3(8, 4), dim3(256), 0, stream>>>(outb, 1500, fc_final2_w, fc_final2_b, y1, 500, TGT, 500, 1500, 0);

  k_logsoftmax<<<dim3(TGT), dim3(1024), 0, stream>>>(score);
}